// Round 1
// baseline (685.101 us; speedup 1.0000x reference)
//
#include <hip/hip_runtime.h>
#include <hip/hip_bf16.h>
#include <math.h>

#define NN 100000
#define EE 1600000

// ---------------- CSR construction ----------------

__global__ __launch_bounds__(256) void k_count(const int* __restrict__ src, int* __restrict__ cnt, int E) {
    int e = blockIdx.x * 256 + threadIdx.x;
    if (e < E) atomicAdd(&cnt[src[e]], 1);
}

__global__ __launch_bounds__(1024) void k_scan_block(const int* __restrict__ cnt, int* __restrict__ tmp_scan,
                                                     int* __restrict__ bsum, int n) {
    __shared__ int s[1024];
    int t = threadIdx.x;
    int g = blockIdx.x * 1024 + t;
    int v = (g < n) ? cnt[g] : 0;
    s[t] = v;
    __syncthreads();
    for (int off = 1; off < 1024; off <<= 1) {
        int x = (t >= off) ? s[t - off] : 0;
        __syncthreads();
        s[t] += x;
        __syncthreads();
    }
    if (g < n) tmp_scan[g] = s[t];
    if (t == 1023) bsum[blockIdx.x] = s[1023];
}

__global__ __launch_bounds__(128) void k_scan_bsum(const int* __restrict__ bsum, int* __restrict__ boffs, int nb) {
    __shared__ int s[128];
    int t = threadIdx.x;
    s[t] = (t < nb) ? bsum[t] : 0;
    __syncthreads();
    for (int off = 1; off < 128; off <<= 1) {
        int x = (t >= off) ? s[t - off] : 0;
        __syncthreads();
        s[t] += x;
        __syncthreads();
    }
    if (t < nb) boffs[t] = (t == 0) ? 0 : s[t - 1];
}

__global__ __launch_bounds__(256) void k_finalize(const int* __restrict__ tmp_scan, const int* __restrict__ boffs,
                                                  const int* __restrict__ cnt, int* __restrict__ row_start,
                                                  int* __restrict__ cursor, float* __restrict__ nrm, int n) {
    int i = blockIdx.x * 256 + threadIdx.x;
    if (i > n) return;
    int rs = (i == 0) ? 0 : (tmp_scan[i - 1] + boffs[(i - 1) >> 10]);
    row_start[i] = rs;
    if (i < n) {
        cursor[i] = rs;
        nrm[i] = (float)(1.0 / sqrt((double)cnt[i]));
    }
}

__global__ __launch_bounds__(256) void k_scatter(const int* __restrict__ src, const int* __restrict__ dst,
                                                 int* __restrict__ cursor, int* __restrict__ perm, int E) {
    int e = blockIdx.x * 256 + threadIdx.x;
    if (e < E) {
        int pos = atomicAdd(&cursor[src[e]], 1);
        perm[pos] = dst[e];
    }
}

// ---------------- small helper: v0[k] = sum_j w_rate0[k][j] ----------------

__global__ __launch_bounds__(128) void k_rowsum(const float* __restrict__ w, float* __restrict__ v0) {
    int k = threadIdx.x;
    float s = 0.f;
    for (int j = 0; j < 128; ++j) s += w[k * 128 + j];
    v0[k] = s;
}

// ---------------- matmul: Y[row] = (scale(row) * X[row]) @ W ----------------
// Tile: 64 rows x 64 cols per block (gridDim.y = 2 col halves), K=128.
// LDS: Ws 128x64 (32KB) + Xs transposed 128x64 (32KB) = 64KB.

__global__ __launch_bounds__(256) void k_mm(const float* __restrict__ X, const float* __restrict__ Wg,
                                            const float* __restrict__ nrm, float* __restrict__ Y,
                                            int n, int normPow) {
    __shared__ float Ws[128 * 64];
    __shared__ float Xs[128 * 64];
    int t = threadIdx.x;
    int row0 = blockIdx.x * 64;
    int col0 = blockIdx.y * 64;

    // stage W columns [col0, col0+64)
    {
        const float4* Wg4 = (const float4*)Wg;  // [128][32] float4
        float4* Ws4 = (float4*)Ws;              // [128][16] float4
        #pragma unroll
        for (int i = 0; i < 8; ++i) {
            int f = i * 256 + t;          // 0..2047
            int k = f >> 4;               // row of W
            int j4 = f & 15;              // float4 col within tile
            Ws4[k * 16 + j4] = Wg4[k * 32 + (col0 >> 2) + j4];
        }
    }
    // stage X tile transposed, scaled: Xs[k*64 + r] = scale * X[row0+r][k]
    {
        int r = t >> 2;
        int ko = (t & 3) * 32;
        int row = row0 + r;
        int rowc = row < n ? row : (n - 1);
        float s = 0.f;
        if (row < n) {
            float nv = nrm[row];
            s = (normPow == 2) ? nv * nv : nv;
        }
        const float4* Xr = (const float4*)(X + (size_t)rowc * 128 + ko);
        #pragma unroll
        for (int j = 0; j < 8; ++j) {
            float4 v = Xr[j];
            int k = ko + j * 4;
            Xs[(k + 0) * 64 + r] = v.x * s;
            Xs[(k + 1) * 64 + r] = v.y * s;
            Xs[(k + 2) * 64 + r] = v.z * s;
            Xs[(k + 3) * 64 + r] = v.w * s;
        }
    }
    __syncthreads();

    int rt = (t & 15) * 4;   // 4 rows
    int ct = (t >> 4) * 4;   // 4 cols
    float acc[4][4];
    #pragma unroll
    for (int a = 0; a < 4; ++a)
        #pragma unroll
        for (int b = 0; b < 4; ++b) acc[a][b] = 0.f;

    #pragma unroll 4
    for (int k = 0; k < 128; ++k) {
        float4 xv = *(const float4*)(Xs + k * 64 + rt);
        float4 wv = *(const float4*)(Ws + k * 64 + ct);
        float xr[4] = {xv.x, xv.y, xv.z, xv.w};
        float wc[4] = {wv.x, wv.y, wv.z, wv.w};
        #pragma unroll
        for (int a = 0; a < 4; ++a)
            #pragma unroll
            for (int b = 0; b < 4; ++b)
                acc[a][b] += xr[a] * wc[b];
    }

    #pragma unroll
    for (int a = 0; a < 4; ++a) {
        int row = row0 + rt + a;
        if (row < n) {
            float4 o = make_float4(acc[a][0], acc[a][1], acc[a][2], acc[a][3]);
            *(float4*)(Y + (size_t)row * 128 + col0 + ct) = o;
        }
    }
}

// ---------------- aggregation: B[i] = sum_{e in CSR row i} A[perm[e]] ----------------
// one wave per node; lane holds float2 (cols 2L, 2L+1)

__global__ __launch_bounds__(256) void k_agg(const float* __restrict__ A, const int* __restrict__ row_start,
                                             const int* __restrict__ perm, float* __restrict__ B, int n) {
    int wid = (blockIdx.x * 256 + threadIdx.x) >> 6;
    int lane = threadIdx.x & 63;
    if (wid >= n) return;
    int s = row_start[wid], e = row_start[wid + 1];
    float ax0 = 0, ay0 = 0, ax1 = 0, ay1 = 0, ax2 = 0, ay2 = 0, ax3 = 0, ay3 = 0;
    int i = s;
    for (; i + 4 <= e; i += 4) {
        int d0 = perm[i], d1 = perm[i + 1], d2 = perm[i + 2], d3 = perm[i + 3];
        float2 v0 = *(const float2*)(A + (size_t)d0 * 128 + lane * 2);
        float2 v1 = *(const float2*)(A + (size_t)d1 * 128 + lane * 2);
        float2 v2 = *(const float2*)(A + (size_t)d2 * 128 + lane * 2);
        float2 v3 = *(const float2*)(A + (size_t)d3 * 128 + lane * 2);
        ax0 += v0.x; ay0 += v0.y;
        ax1 += v1.x; ay1 += v1.y;
        ax2 += v2.x; ay2 += v2.y;
        ax3 += v3.x; ay3 += v3.y;
    }
    for (; i < e; ++i) {
        int d = perm[i];
        float2 v = *(const float2*)(A + (size_t)d * 128 + lane * 2);
        ax0 += v.x; ay0 += v.y;
    }
    float2 acc = make_float2((ax0 + ax1) + (ax2 + ax3), (ay0 + ay1) + (ay2 + ay3));
    *(float2*)(B + (size_t)wid * 128 + lane * 2) = acc;
}

// ---------------- aggregation 2 + fused projection epilogue ----------------
// h2 = norm[i] * sum A[perm[e]];  r0s=h2.v0, r1=h2.w_rate1, a=h2.w_alpha

__global__ __launch_bounds__(256) void k_agg2(const float* __restrict__ A, const int* __restrict__ row_start,
                                              const int* __restrict__ perm, const float* __restrict__ nrm,
                                              const float* __restrict__ v0, const float* __restrict__ w_rate1,
                                              const float* __restrict__ w_alpha,
                                              float* __restrict__ r0s, float* __restrict__ r1v,
                                              float* __restrict__ av, int n) {
    int wid = (blockIdx.x * 256 + threadIdx.x) >> 6;
    int lane = threadIdx.x & 63;
    if (wid >= n) return;
    int s = row_start[wid], e = row_start[wid + 1];
    float ax0 = 0, ay0 = 0, ax1 = 0, ay1 = 0, ax2 = 0, ay2 = 0, ax3 = 0, ay3 = 0;
    int i = s;
    for (; i + 4 <= e; i += 4) {
        int d0 = perm[i], d1 = perm[i + 1], d2 = perm[i + 2], d3 = perm[i + 3];
        float2 v0g = *(const float2*)(A + (size_t)d0 * 128 + lane * 2);
        float2 v1g = *(const float2*)(A + (size_t)d1 * 128 + lane * 2);
        float2 v2g = *(const float2*)(A + (size_t)d2 * 128 + lane * 2);
        float2 v3g = *(const float2*)(A + (size_t)d3 * 128 + lane * 2);
        ax0 += v0g.x; ay0 += v0g.y;
        ax1 += v1g.x; ay1 += v1g.y;
        ax2 += v2g.x; ay2 += v2g.y;
        ax3 += v3g.x; ay3 += v3g.y;
    }
    for (; i < e; ++i) {
        int d = perm[i];
        float2 v = *(const float2*)(A + (size_t)d * 128 + lane * 2);
        ax0 += v.x; ay0 += v.y;
    }
    float hx = (ax0 + ax1) + (ax2 + ax3);
    float hy = (ay0 + ay1) + (ay2 + ay3);
    float nv = nrm[wid];
    hx *= nv; hy *= nv;

    float2 c0 = *(const float2*)(v0 + lane * 2);
    float2 c1 = *(const float2*)(w_rate1 + lane * 2);
    float2 c2 = *(const float2*)(w_alpha + lane * 2);
    float p0 = hx * c0.x + hy * c0.y;
    float p1 = hx * c1.x + hy * c1.y;
    float p2 = hx * c2.x + hy * c2.y;
    #pragma unroll
    for (int off = 32; off > 0; off >>= 1) {
        p0 += __shfl_down(p0, off);
        p1 += __shfl_down(p1, off);
        p2 += __shfl_down(p2, off);
    }
    if (lane == 0) {
        r0s[wid] = p0;
        r1v[wid] = p1;
        av[wid] = p2;
    }
}

// ---------------- edge outputs ----------------

__global__ __launch_bounds__(256) void k_edge_out(const int* __restrict__ esrc, const int* __restrict__ edst,
                                                  const int* __restrict__ sfake, const int* __restrict__ dfake,
                                                  const float* __restrict__ r0s, const float* __restrict__ r1v,
                                                  const float* __restrict__ av, float* __restrict__ out,
                                                  int E, int n) {
    int e = blockIdx.x * 256 + threadIdx.x;
    if (e >= E) return;
    int s = esrc[e], d = edst[e];
    int sf = sfake[e]; sf = sf < 0 ? 0 : (sf >= n ? n - 1 : sf);
    int df = dfake[e]; df = df < 0 ? 0 : (df >= n ? n - 1 : df);
    float as = av[s], ad = av[d], adf = av[df];
    out[e]             = expf(r0s[s] + r0s[d]);
    out[(size_t)E + e] = expf(r1v[s] + r1v[d]);
    out[(size_t)2 * E + e] = 1.f / (1.f + expf(-(as * ad)));
    out[(size_t)3 * E + e] = expf(r0s[sf] + 128.f * r1v[df]);
    out[(size_t)4 * E + e] = expf(r1v[sf] + r1v[df]);
    out[(size_t)5 * E + e] = 1.f / (1.f + expf(-(as * adf)));
}

// ---------------- launch ----------------

extern "C" void kernel_launch(void* const* d_in, const int* in_sizes, int n_in,
                              void* d_out, int out_size, void* d_ws, size_t ws_size,
                              hipStream_t stream) {
    const float* h       = (const float*)d_in[0];
    const float* w_gcn0  = (const float*)d_in[1];
    const float* w_gcn1  = (const float*)d_in[2];
    const float* w_rate0 = (const float*)d_in[3];
    const float* w_rate1 = (const float*)d_in[4];
    const float* w_alpha = (const float*)d_in[5];
    const int* edge_src  = (const int*)d_in[6];
    const int* edge_dst  = (const int*)d_in[7];
    const int* src_fake  = (const int*)d_in[8];
    const int* dst_fake  = (const int*)d_in[9];
    float* out = (float*)d_out;

    const int N = NN, E = EE;

    char* p = (char*)d_ws;
    auto alloc = [&](size_t bytes) {
        char* r = p;
        p += (bytes + 255) & ~(size_t)255;
        return r;
    };
    float* A       = (float*)alloc((size_t)N * 128 * 4);
    float* B       = (float*)alloc((size_t)N * 128 * 4);
    int* perm      = (int*)alloc((size_t)E * 4);
    int* cnt       = (int*)alloc((size_t)N * 4);
    int* tmp_scan  = (int*)alloc((size_t)N * 4);
    int* row_start = (int*)alloc((size_t)(N + 1) * 4);
    int* cursor    = (int*)alloc((size_t)N * 4);
    float* nrm     = (float*)alloc((size_t)N * 4);
    float* r0s     = (float*)alloc((size_t)N * 4);
    float* r1v     = (float*)alloc((size_t)N * 4);
    float* av      = (float*)alloc((size_t)N * 4);
    float* v0      = (float*)alloc(512);
    int* bsum      = (int*)alloc(512);
    int* boffs     = (int*)alloc(512);

    hipMemsetAsync(cnt, 0, (size_t)N * 4, stream);

    int ebl = (E + 255) / 256;
    k_count<<<ebl, 256, 0, stream>>>(edge_src, cnt, E);
    int nb = (N + 1023) / 1024;
    k_scan_block<<<nb, 1024, 0, stream>>>(cnt, tmp_scan, bsum, N);
    k_scan_bsum<<<1, 128, 0, stream>>>(bsum, boffs, nb);
    k_finalize<<<(N + 1 + 255) / 256, 256, 0, stream>>>(tmp_scan, boffs, cnt, row_start, cursor, nrm, N);
    k_scatter<<<ebl, 256, 0, stream>>>(edge_src, edge_dst, cursor, perm, E);
    k_rowsum<<<1, 128, 0, stream>>>(w_rate0, v0);

    dim3 mmg((N + 63) / 64, 2);
    int aggb = (N * 64 + 255) / 256;

    k_mm<<<mmg, 256, 0, stream>>>(h, w_gcn0, nrm, A, N, 1);
    k_agg<<<aggb, 256, 0, stream>>>(A, row_start, perm, B, N);
    k_mm<<<mmg, 256, 0, stream>>>(B, w_gcn1, nrm, A, N, 2);
    k_agg2<<<aggb, 256, 0, stream>>>(A, row_start, perm, nrm, v0, w_rate1, w_alpha, r0s, r1v, av, N);
    k_edge_out<<<ebl, 256, 0, stream>>>(edge_src, edge_dst, src_fake, dst_fake, r0s, r1v, av, out, E, N);
}

// Round 2
// 597.762 us; speedup vs baseline: 1.1461x; 1.1461x over previous
//
#include <hip/hip_runtime.h>
#include <hip/hip_bf16.h>
#include <math.h>

#define NN 100000
#define EE 1600000
#define KB 256          // buckets
#define RR 391          // ceil(NN / KB)
#define BCAP 12288      // LDS staging capacity per bucket (avg ~6250)

// ---------------- degree count ----------------

__global__ __launch_bounds__(256) void k_count(const int* __restrict__ src, int* __restrict__ cnt, int E) {
    int e = blockIdx.x * 256 + threadIdx.x;
    if (e < E) atomicAdd(&cnt[src[e]], 1);
}

__global__ __launch_bounds__(1024) void k_scan_block(const int* __restrict__ cnt, int* __restrict__ tmp_scan,
                                                     int* __restrict__ bsum, int n) {
    __shared__ int s[1024];
    int t = threadIdx.x;
    int g = blockIdx.x * 1024 + t;
    int v = (g < n) ? cnt[g] : 0;
    s[t] = v;
    __syncthreads();
    for (int off = 1; off < 1024; off <<= 1) {
        int x = (t >= off) ? s[t - off] : 0;
        __syncthreads();
        s[t] += x;
        __syncthreads();
    }
    if (g < n) tmp_scan[g] = s[t];
    if (t == 1023) bsum[blockIdx.x] = s[1023];
}

__global__ __launch_bounds__(128) void k_scan_bsum(const int* __restrict__ bsum, int* __restrict__ boffs, int nb) {
    __shared__ int s[128];
    int t = threadIdx.x;
    s[t] = (t < nb) ? bsum[t] : 0;
    __syncthreads();
    for (int off = 1; off < 128; off <<= 1) {
        int x = (t >= off) ? s[t - off] : 0;
        __syncthreads();
        s[t] += x;
        __syncthreads();
    }
    if (t < nb) boffs[t] = (t == 0) ? 0 : s[t - 1];
}

__global__ __launch_bounds__(256) void k_finalize(const int* __restrict__ tmp_scan, const int* __restrict__ boffs,
                                                  const int* __restrict__ cnt, int* __restrict__ row_start,
                                                  float* __restrict__ nrm, int n) {
    int i = blockIdx.x * 256 + threadIdx.x;
    if (i > n) return;
    int rs = (i == 0) ? 0 : (tmp_scan[i - 1] + boffs[(i - 1) >> 10]);
    row_start[i] = rs;
    if (i < n) {
        nrm[i] = (float)(1.0 / sqrt((double)cnt[i]));
    }
}

__global__ __launch_bounds__(256) void k_init_gcur(const int* __restrict__ row_start, int* __restrict__ gcur, int n) {
    int b = threadIdx.x;  // 256 threads, 1 block
    int node = b * RR;
    if (node > n) node = n;
    gcur[b] = row_start[node];
}

// ---------------- two-phase bucketed scatter ----------------
// Phase A: partition edges into KB buckets (by src / RR); packed word = dst | (src_rel << 17).

__global__ __launch_bounds__(256) void k_partA(const int* __restrict__ src, const int* __restrict__ dst,
                                               int* __restrict__ gcur, unsigned int* __restrict__ pk, int E) {
    __shared__ int cnt[KB];
    __shared__ int base[KB];
    int t = threadIdx.x;
    int e0 = blockIdx.x * 4096;
    cnt[t] = 0;
    __syncthreads();
    unsigned int pkv[16];
    int bkt[16];
    #pragma unroll
    for (int i = 0; i < 16; ++i) {
        int e = e0 + i * 256 + t;
        if (e < E) {
            int s = src[e];
            int d = dst[e];
            int b = s / RR;
            bkt[i] = b;
            pkv[i] = (unsigned int)d | ((unsigned int)(s - b * RR) << 17);
            atomicAdd(&cnt[b], 1);
        } else {
            bkt[i] = -1;
        }
    }
    __syncthreads();
    base[t] = (cnt[t] > 0) ? atomicAdd(&gcur[t], cnt[t]) : 0;
    __syncthreads();
    cnt[t] = 0;
    __syncthreads();
    #pragma unroll
    for (int i = 0; i < 16; ++i) {
        if (bkt[i] >= 0) {
            int r = atomicAdd(&cnt[bkt[i]], 1);
            pk[base[bkt[i]] + r] = pkv[i];
        }
    }
}

// Phase B: one block per bucket; LDS position-scatter then coalesced flush.

__global__ __launch_bounds__(256) void k_partB(const unsigned int* __restrict__ pk,
                                               const int* __restrict__ row_start,
                                               int* __restrict__ perm, int n) {
    __shared__ int cur[RR];
    __shared__ int buf[BCAP];
    int b = blockIdx.x;
    int t = threadIdx.x;
    int nlo = b * RR;
    int nhi = nlo + RR; if (nhi > n) nhi = n;
    if (nlo >= n) return;
    int P0 = row_start[nlo];
    int P1 = row_start[nhi];
    for (int i = t; i < nhi - nlo; i += 256) cur[i] = row_start[nlo + i] - P0;
    __syncthreads();
    int m = P1 - P0;
    for (int i = t; i < m; i += 256) {
        unsigned int w = pk[P0 + i];
        int srel = (int)(w >> 17);
        int d = (int)(w & 0x1FFFFu);
        int pos = atomicAdd(&cur[srel], 1);
        if (pos < BCAP) buf[pos] = d;
    }
    __syncthreads();
    for (int i = t; i < m; i += 256) perm[P0 + i] = buf[i];
}

// ---------------- small helper: v0[k] = sum_j w_rate0[k][j] ----------------

__global__ __launch_bounds__(128) void k_rowsum(const float* __restrict__ w, float* __restrict__ v0) {
    int k = threadIdx.x;
    float s = 0.f;
    for (int j = 0; j < 128; ++j) s += w[k * 128 + j];
    v0[k] = s;
}

// ---------------- matmul: Y[row] = (scale(row) * X[row]) @ W ----------------

__global__ __launch_bounds__(256) void k_mm(const float* __restrict__ X, const float* __restrict__ Wg,
                                            const float* __restrict__ nrm, float* __restrict__ Y,
                                            int n, int normPow) {
    __shared__ float Ws[128 * 64];
    __shared__ float Xs[128 * 64];
    int t = threadIdx.x;
    int row0 = blockIdx.x * 64;
    int col0 = blockIdx.y * 64;

    {
        const float4* Wg4 = (const float4*)Wg;
        float4* Ws4 = (float4*)Ws;
        #pragma unroll
        for (int i = 0; i < 8; ++i) {
            int f = i * 256 + t;
            int k = f >> 4;
            int j4 = f & 15;
            Ws4[k * 16 + j4] = Wg4[k * 32 + (col0 >> 2) + j4];
        }
    }
    {
        int r = t >> 2;
        int ko = (t & 3) * 32;
        int row = row0 + r;
        int rowc = row < n ? row : (n - 1);
        float s = 0.f;
        if (row < n) {
            float nv = nrm[row];
            s = (normPow == 2) ? nv * nv : nv;
        }
        const float4* Xr = (const float4*)(X + (size_t)rowc * 128 + ko);
        #pragma unroll
        for (int j = 0; j < 8; ++j) {
            float4 v = Xr[j];
            int k = ko + j * 4;
            Xs[(k + 0) * 64 + r] = v.x * s;
            Xs[(k + 1) * 64 + r] = v.y * s;
            Xs[(k + 2) * 64 + r] = v.z * s;
            Xs[(k + 3) * 64 + r] = v.w * s;
        }
    }
    __syncthreads();

    int rt = (t & 15) * 4;
    int ct = (t >> 4) * 4;
    float acc[4][4];
    #pragma unroll
    for (int a = 0; a < 4; ++a)
        #pragma unroll
        for (int b = 0; b < 4; ++b) acc[a][b] = 0.f;

    #pragma unroll 4
    for (int k = 0; k < 128; ++k) {
        float4 xv = *(const float4*)(Xs + k * 64 + rt);
        float4 wv = *(const float4*)(Ws + k * 64 + ct);
        float xr[4] = {xv.x, xv.y, xv.z, xv.w};
        float wc[4] = {wv.x, wv.y, wv.z, wv.w};
        #pragma unroll
        for (int a = 0; a < 4; ++a)
            #pragma unroll
            for (int b = 0; b < 4; ++b)
                acc[a][b] += xr[a] * wc[b];
    }

    #pragma unroll
    for (int a = 0; a < 4; ++a) {
        int row = row0 + rt + a;
        if (row < n) {
            float4 o = make_float4(acc[a][0], acc[a][1], acc[a][2], acc[a][3]);
            *(float4*)(Y + (size_t)row * 128 + col0 + ct) = o;
        }
    }
}

// ---------------- aggregation: B[i] = sum_{e in CSR row i} A[perm[e]] ----------------
// half-wave (32 lanes, float4) per node; 2 nodes per wave

__global__ __launch_bounds__(256) void k_agg(const float* __restrict__ A, const int* __restrict__ row_start,
                                             const int* __restrict__ perm, float* __restrict__ B, int n) {
    int wid = (blockIdx.x * 256 + threadIdx.x) >> 6;
    int lane = threadIdx.x & 63;
    int node = wid * 2 + (lane >> 5);
    int c4 = (lane & 31) * 4;
    if (node >= n) return;
    int s = row_start[node], e = row_start[node + 1];
    float4 a0 = make_float4(0, 0, 0, 0), a1 = a0, a2 = a0, a3 = a0;
    int i = s;
    for (; i + 4 <= e; i += 4) {
        int d0 = perm[i], d1 = perm[i + 1], d2 = perm[i + 2], d3 = perm[i + 3];
        float4 v0 = *(const float4*)(A + (size_t)d0 * 128 + c4);
        float4 v1 = *(const float4*)(A + (size_t)d1 * 128 + c4);
        float4 v2 = *(const float4*)(A + (size_t)d2 * 128 + c4);
        float4 v3 = *(const float4*)(A + (size_t)d3 * 128 + c4);
        a0.x += v0.x; a0.y += v0.y; a0.z += v0.z; a0.w += v0.w;
        a1.x += v1.x; a1.y += v1.y; a1.z += v1.z; a1.w += v1.w;
        a2.x += v2.x; a2.y += v2.y; a2.z += v2.z; a2.w += v2.w;
        a3.x += v3.x; a3.y += v3.y; a3.z += v3.z; a3.w += v3.w;
    }
    for (; i < e; ++i) {
        int d = perm[i];
        float4 v = *(const float4*)(A + (size_t)d * 128 + c4);
        a0.x += v.x; a0.y += v.y; a0.z += v.z; a0.w += v.w;
    }
    float4 acc;
    acc.x = (a0.x + a1.x) + (a2.x + a3.x);
    acc.y = (a0.y + a1.y) + (a2.y + a3.y);
    acc.z = (a0.z + a1.z) + (a2.z + a3.z);
    acc.w = (a0.w + a1.w) + (a2.w + a3.w);
    *(float4*)(B + (size_t)node * 128 + c4) = acc;
}

// ---------------- aggregation 2 + fused projection epilogue ----------------

__global__ __launch_bounds__(256) void k_agg2(const float* __restrict__ A, const int* __restrict__ row_start,
                                              const int* __restrict__ perm, const float* __restrict__ nrm,
                                              const float* __restrict__ v0, const float* __restrict__ w_rate1,
                                              const float* __restrict__ w_alpha,
                                              float* __restrict__ r0s, float* __restrict__ r1v,
                                              float* __restrict__ av, int n) {
    int wid = (blockIdx.x * 256 + threadIdx.x) >> 6;
    int lane = threadIdx.x & 63;
    int node = wid * 2 + (lane >> 5);
    int c4 = (lane & 31) * 4;
    if (node >= n) return;
    int s = row_start[node], e = row_start[node + 1];
    float4 a0 = make_float4(0, 0, 0, 0), a1 = a0, a2 = a0, a3 = a0;
    int i = s;
    for (; i + 4 <= e; i += 4) {
        int d0 = perm[i], d1 = perm[i + 1], d2 = perm[i + 2], d3 = perm[i + 3];
        float4 g0 = *(const float4*)(A + (size_t)d0 * 128 + c4);
        float4 g1 = *(const float4*)(A + (size_t)d1 * 128 + c4);
        float4 g2 = *(const float4*)(A + (size_t)d2 * 128 + c4);
        float4 g3 = *(const float4*)(A + (size_t)d3 * 128 + c4);
        a0.x += g0.x; a0.y += g0.y; a0.z += g0.z; a0.w += g0.w;
        a1.x += g1.x; a1.y += g1.y; a1.z += g1.z; a1.w += g1.w;
        a2.x += g2.x; a2.y += g2.y; a2.z += g2.z; a2.w += g2.w;
        a3.x += g3.x; a3.y += g3.y; a3.z += g3.z; a3.w += g3.w;
    }
    for (; i < e; ++i) {
        int d = perm[i];
        float4 g = *(const float4*)(A + (size_t)d * 128 + c4);
        a0.x += g.x; a0.y += g.y; a0.z += g.z; a0.w += g.w;
    }
    float4 hv;
    float nv = nrm[node];
    hv.x = ((a0.x + a1.x) + (a2.x + a3.x)) * nv;
    hv.y = ((a0.y + a1.y) + (a2.y + a3.y)) * nv;
    hv.z = ((a0.z + a1.z) + (a2.z + a3.z)) * nv;
    hv.w = ((a0.w + a1.w) + (a2.w + a3.w)) * nv;

    float4 c0 = *(const float4*)(v0 + c4);
    float4 c1 = *(const float4*)(w_rate1 + c4);
    float4 c2 = *(const float4*)(w_alpha + c4);
    float p0 = hv.x * c0.x + hv.y * c0.y + hv.z * c0.z + hv.w * c0.w;
    float p1 = hv.x * c1.x + hv.y * c1.y + hv.z * c1.z + hv.w * c1.w;
    float p2 = hv.x * c2.x + hv.y * c2.y + hv.z * c2.z + hv.w * c2.w;
    #pragma unroll
    for (int off = 16; off > 0; off >>= 1) {
        p0 += __shfl_down(p0, off, 32);
        p1 += __shfl_down(p1, off, 32);
        p2 += __shfl_down(p2, off, 32);
    }
    if ((lane & 31) == 0) {
        r0s[node] = p0;
        r1v[node] = p1;
        av[node] = p2;
    }
}

// ---------------- edge outputs ----------------

__global__ __launch_bounds__(256) void k_edge_out(const int* __restrict__ esrc, const int* __restrict__ edst,
                                                  const int* __restrict__ sfake, const int* __restrict__ dfake,
                                                  const float* __restrict__ r0s, const float* __restrict__ r1v,
                                                  const float* __restrict__ av, float* __restrict__ out,
                                                  int E, int n) {
    int e = blockIdx.x * 256 + threadIdx.x;
    if (e >= E) return;
    int s = esrc[e], d = edst[e];
    int sf = sfake[e]; sf = sf < 0 ? 0 : (sf >= n ? n - 1 : sf);
    int df = dfake[e]; df = df < 0 ? 0 : (df >= n ? n - 1 : df);
    float as = av[s], ad = av[d], adf = av[df];
    out[e]             = expf(r0s[s] + r0s[d]);
    out[(size_t)E + e] = expf(r1v[s] + r1v[d]);
    out[(size_t)2 * E + e] = 1.f / (1.f + expf(-(as * ad)));
    out[(size_t)3 * E + e] = expf(r0s[sf] + 128.f * r1v[df]);
    out[(size_t)4 * E + e] = expf(r1v[sf] + r1v[df]);
    out[(size_t)5 * E + e] = 1.f / (1.f + expf(-(as * adf)));
}

// ---------------- launch ----------------

extern "C" void kernel_launch(void* const* d_in, const int* in_sizes, int n_in,
                              void* d_out, int out_size, void* d_ws, size_t ws_size,
                              hipStream_t stream) {
    const float* h       = (const float*)d_in[0];
    const float* w_gcn0  = (const float*)d_in[1];
    const float* w_gcn1  = (const float*)d_in[2];
    const float* w_rate0 = (const float*)d_in[3];
    const float* w_rate1 = (const float*)d_in[4];
    const float* w_alpha = (const float*)d_in[5];
    const int* edge_src  = (const int*)d_in[6];
    const int* edge_dst  = (const int*)d_in[7];
    const int* src_fake  = (const int*)d_in[8];
    const int* dst_fake  = (const int*)d_in[9];
    float* out = (float*)d_out;

    const int N = NN, E = EE;

    char* p = (char*)d_ws;
    auto alloc = [&](size_t bytes) {
        char* r = p;
        p += (bytes + 255) & ~(size_t)255;
        return r;
    };
    float* A        = (float*)alloc((size_t)N * 128 * 4);
    float* B        = (float*)alloc((size_t)N * 128 * 4);
    int* perm       = (int*)alloc((size_t)E * 4);
    unsigned int* pk = (unsigned int*)alloc((size_t)E * 4);
    int* cnt        = (int*)alloc((size_t)N * 4);
    int* tmp_scan   = (int*)alloc((size_t)N * 4);
    int* row_start  = (int*)alloc((size_t)(N + 1) * 4);
    float* nrm      = (float*)alloc((size_t)N * 4);
    float* r0s      = (float*)alloc((size_t)N * 4);
    float* r1v      = (float*)alloc((size_t)N * 4);
    float* av       = (float*)alloc((size_t)N * 4);
    float* v0       = (float*)alloc(512);
    int* bsum       = (int*)alloc(512);
    int* boffs      = (int*)alloc(512);
    int* gcur       = (int*)alloc(KB * 4);

    hipMemsetAsync(cnt, 0, (size_t)N * 4, stream);

    int ebl = (E + 255) / 256;
    k_count<<<ebl, 256, 0, stream>>>(edge_src, cnt, E);
    int nb = (N + 1023) / 1024;
    k_scan_block<<<nb, 1024, 0, stream>>>(cnt, tmp_scan, bsum, N);
    k_scan_bsum<<<1, 128, 0, stream>>>(bsum, boffs, nb);
    k_finalize<<<(N + 1 + 255) / 256, 256, 0, stream>>>(tmp_scan, boffs, cnt, row_start, nrm, N);
    k_init_gcur<<<1, KB, 0, stream>>>(row_start, gcur, N);
    k_partA<<<(E + 4095) / 4096, 256, 0, stream>>>(edge_src, edge_dst, gcur, pk, E);
    k_partB<<<KB, 256, 0, stream>>>(pk, row_start, perm, N);
    k_rowsum<<<1, 128, 0, stream>>>(w_rate0, v0);

    dim3 mmg((N + 63) / 64, 2);
    int aggb = (((N + 1) / 2) * 64 + 255) / 256;

    k_mm<<<mmg, 256, 0, stream>>>(h, w_gcn0, nrm, A, N, 1);
    k_agg<<<aggb, 256, 0, stream>>>(A, row_start, perm, B, N);
    k_mm<<<mmg, 256, 0, stream>>>(B, w_gcn1, nrm, A, N, 2);
    k_agg2<<<aggb, 256, 0, stream>>>(A, row_start, perm, nrm, v0, w_rate1, w_alpha, r0s, r1v, av, N);
    k_edge_out<<<ebl, 256, 0, stream>>>(edge_src, edge_dst, src_fake, dst_fake, r0s, r1v, av, out, E, N);
}

// Round 3
// 391.472 us; speedup vs baseline: 1.7501x; 1.5270x over previous
//
#include <hip/hip_runtime.h>
#include <hip/hip_bf16.h>
#include <math.h>

#define NN 100000
#define EE 1600000
#define KB 256          // buckets
#define RR 391          // ceil(NN / KB)
#define BCAP 12288      // LDS staging capacity per bucket (avg ~6250, 96 sigma margin)

// ---------------- bucket histogram (per-block LDS, then global) ----------------

__global__ __launch_bounds__(256) void k_countB(const int* __restrict__ src, int* __restrict__ gbcnt, int E) {
    __shared__ int c[KB];
    int t = threadIdx.x;
    c[t] = 0;
    __syncthreads();
    int e0 = blockIdx.x * 4096;
    #pragma unroll
    for (int i = 0; i < 16; ++i) {
        int e = e0 + i * 256 + t;
        if (e < E) atomicAdd(&c[src[e] / RR], 1);
    }
    __syncthreads();
    if (c[t] > 0) atomicAdd(&gbcnt[t], c[t]);
}

// ---------------- scan 256 bucket totals -> bstart[257], gcur ----------------

__global__ __launch_bounds__(256) void k_bscan(const int* __restrict__ gbcnt, int* __restrict__ bstart,
                                               int* __restrict__ gcur, int E) {
    __shared__ int s[KB];
    int t = threadIdx.x;
    s[t] = gbcnt[t];
    __syncthreads();
    for (int off = 1; off < KB; off <<= 1) {
        int x = (t >= off) ? s[t - off] : 0;
        __syncthreads();
        s[t] += x;
        __syncthreads();
    }
    int excl = (t == 0) ? 0 : s[t - 1];
    bstart[t] = excl;
    gcur[t] = excl;
    if (t == KB - 1) bstart[KB] = E;
}

// ---------------- phase A: partition edges into buckets ----------------
// packed word = dst | (src_rel << 17)   (dst < 2^17, src_rel < 391 < 2^9)

__global__ __launch_bounds__(256) void k_partA(const int* __restrict__ src, const int* __restrict__ dst,
                                               int* __restrict__ gcur, unsigned int* __restrict__ pk, int E) {
    __shared__ int cnt[KB];
    __shared__ int base[KB];
    int t = threadIdx.x;
    int e0 = blockIdx.x * 4096;
    cnt[t] = 0;
    __syncthreads();
    unsigned int pkv[16];
    int bkt[16];
    #pragma unroll
    for (int i = 0; i < 16; ++i) {
        int e = e0 + i * 256 + t;
        if (e < E) {
            int s = src[e];
            int d = dst[e];
            int b = s / RR;
            bkt[i] = b;
            pkv[i] = (unsigned int)d | ((unsigned int)(s - b * RR) << 17);
            atomicAdd(&cnt[b], 1);
        } else {
            bkt[i] = -1;
        }
    }
    __syncthreads();
    base[t] = (cnt[t] > 0) ? atomicAdd(&gcur[t], cnt[t]) : 0;
    __syncthreads();
    cnt[t] = 0;
    __syncthreads();
    #pragma unroll
    for (int i = 0; i < 16; ++i) {
        if (bkt[i] >= 0) {
            int r = atomicAdd(&cnt[bkt[i]], 1);
            pk[base[bkt[i]] + r] = pkv[i];
        }
    }
}

// ---------------- phase B: per-bucket CSR finalize + position scatter ----------------
// Derives row_start + nrm (in-LDS 391-scan), scatters dst into LDS, coalesced flush.

__global__ __launch_bounds__(256) void k_partB(const unsigned int* __restrict__ pk,
                                               const int* __restrict__ bstart,
                                               int* __restrict__ row_start, float* __restrict__ nrm,
                                               int* __restrict__ perm, int n, int E) {
    __shared__ int s_cnt[RR];
    __shared__ int s_cur[RR];
    __shared__ int dbuf[BCAP];
    int b = blockIdx.x;
    int t = threadIdx.x;
    int nlo = b * RR;
    int nhi = nlo + RR; if (nhi > n) nhi = n;
    if (nlo >= n) return;
    int nn = nhi - nlo;
    int P0 = bstart[b];
    int P1 = bstart[b + 1];
    int m = P1 - P0;

    for (int i = t; i < RR; i += 256) s_cnt[i] = 0;
    __syncthreads();
    // pass 1: per-node counts
    for (int i = t; i < m; i += 256) {
        unsigned int w = pk[P0 + i];
        atomicAdd(&s_cnt[w >> 17], 1);
    }
    __syncthreads();
    // exclusive scan of s_cnt[0..RR) by wave 0 (7 entries per lane)
    if (t < 64) {
        int base0 = t * 7;
        int loc[7];
        int sum = 0;
        #pragma unroll
        for (int j = 0; j < 7; ++j) {
            int idx = base0 + j;
            int c = (idx < RR) ? s_cnt[idx] : 0;
            loc[j] = sum;
            sum += c;
        }
        int pre = sum;
        #pragma unroll
        for (int off = 1; off < 64; off <<= 1) {
            int y = __shfl_up(pre, off);
            if (t >= off) pre += y;
        }
        pre -= sum;  // exclusive
        #pragma unroll
        for (int j = 0; j < 7; ++j) {
            int idx = base0 + j;
            if (idx < RR) s_cur[idx] = pre + loc[j];
        }
    }
    __syncthreads();
    // write row_start + nrm
    for (int i = t; i < nn; i += 256) {
        row_start[nlo + i] = P0 + s_cur[i];
        nrm[nlo + i] = rsqrtf((float)s_cnt[i]);
    }
    if (b == KB - 1 && t == 0) row_start[n] = E;
    __syncthreads();
    // pass 2: position scatter into LDS
    for (int i = t; i < m; i += 256) {
        unsigned int w = pk[P0 + i];
        int pos = atomicAdd(&s_cur[w >> 17], 1);
        if (pos < BCAP) dbuf[pos] = (int)(w & 0x1FFFFu);
    }
    __syncthreads();
    for (int i = t; i < m; i += 256) perm[P0 + i] = dbuf[i];
}

// ---------------- Q = W1 @ [rowsum(w_rate0) | w_rate1 | w_alpha]  (128x3) ----------------

__global__ __launch_bounds__(128) void k_qmat(const float* __restrict__ w_gcn1,
                                              const float* __restrict__ w_rate0,
                                              const float* __restrict__ w_rate1,
                                              const float* __restrict__ w_alpha,
                                              float* __restrict__ Qt0, float* __restrict__ Qt1,
                                              float* __restrict__ Qt2) {
    __shared__ float V0[128], V1[128], V2[128];
    int t = threadIdx.x;
    float s = 0.f;
    for (int j = 0; j < 128; ++j) s += w_rate0[t * 128 + j];
    V0[t] = s;
    V1[t] = w_rate1[t];
    V2[t] = w_alpha[t];
    __syncthreads();
    float q0 = 0.f, q1 = 0.f, q2 = 0.f;
    for (int m = 0; m < 128; ++m) {
        float w = w_gcn1[t * 128 + m];
        q0 += w * V0[m];
        q1 += w * V1[m];
        q2 += w * V2[m];
    }
    Qt0[t] = q0;
    Qt1[t] = q1;
    Qt2[t] = q2;
}

// ---------------- matmul: Y[row] = (nrm(row) * X[row]) @ W ----------------

__global__ __launch_bounds__(256) void k_mm(const float* __restrict__ X, const float* __restrict__ Wg,
                                            const float* __restrict__ nrm, float* __restrict__ Y, int n) {
    __shared__ float Ws[128 * 64];
    __shared__ float Xs[128 * 64];
    int t = threadIdx.x;
    int row0 = blockIdx.x * 64;
    int col0 = blockIdx.y * 64;

    {
        const float4* Wg4 = (const float4*)Wg;
        float4* Ws4 = (float4*)Ws;
        #pragma unroll
        for (int i = 0; i < 8; ++i) {
            int f = i * 256 + t;
            int k = f >> 4;
            int j4 = f & 15;
            Ws4[k * 16 + j4] = Wg4[k * 32 + (col0 >> 2) + j4];
        }
    }
    {
        int r = t >> 2;
        int ko = (t & 3) * 32;
        int row = row0 + r;
        int rowc = row < n ? row : (n - 1);
        float s = 0.f;
        if (row < n) s = nrm[row];
        const float4* Xr = (const float4*)(X + (size_t)rowc * 128 + ko);
        #pragma unroll
        for (int j = 0; j < 8; ++j) {
            float4 v = Xr[j];
            int k = ko + j * 4;
            Xs[(k + 0) * 64 + r] = v.x * s;
            Xs[(k + 1) * 64 + r] = v.y * s;
            Xs[(k + 2) * 64 + r] = v.z * s;
            Xs[(k + 3) * 64 + r] = v.w * s;
        }
    }
    __syncthreads();

    int rt = (t & 15) * 4;
    int ct = (t >> 4) * 4;
    float acc[4][4];
    #pragma unroll
    for (int a = 0; a < 4; ++a)
        #pragma unroll
        for (int b = 0; b < 4; ++b) acc[a][b] = 0.f;

    #pragma unroll 4
    for (int k = 0; k < 128; ++k) {
        float4 xv = *(const float4*)(Xs + k * 64 + rt);
        float4 wv = *(const float4*)(Ws + k * 64 + ct);
        float xr[4] = {xv.x, xv.y, xv.z, xv.w};
        float wc[4] = {wv.x, wv.y, wv.z, wv.w};
        #pragma unroll
        for (int a = 0; a < 4; ++a)
            #pragma unroll
            for (int b = 0; b < 4; ++b)
                acc[a][b] += xr[a] * wc[b];
    }

    #pragma unroll
    for (int a = 0; a < 4; ++a) {
        int row = row0 + rt + a;
        if (row < n) {
            float4 o = make_float4(acc[a][0], acc[a][1], acc[a][2], acc[a][3]);
            *(float4*)(Y + (size_t)row * 128 + col0 + ct) = o;
        }
    }
}

// ---------------- fused gather-aggregate + 128x3 projection ----------------
// z[i] = nrm[i]^2 * (sum_{e in row i} Y[perm[e]]) @ Q      (half-wave per node)

__global__ __launch_bounds__(256) void k_aggz(const float* __restrict__ Y, const int* __restrict__ row_start,
                                              const int* __restrict__ perm, const float* __restrict__ nrm,
                                              const float* __restrict__ Qt0, const float* __restrict__ Qt1,
                                              const float* __restrict__ Qt2, float4* __restrict__ z4, int n) {
    int wid = (blockIdx.x * 256 + threadIdx.x) >> 6;
    int lane = threadIdx.x & 63;
    int node = wid * 2 + (lane >> 5);
    int c4 = (lane & 31) * 4;
    if (node >= n) return;
    int s = row_start[node], e = row_start[node + 1];
    float4 a0 = make_float4(0, 0, 0, 0), a1 = a0, a2 = a0, a3 = a0;
    int i = s;
    for (; i + 4 <= e; i += 4) {
        int d0 = perm[i], d1 = perm[i + 1], d2 = perm[i + 2], d3 = perm[i + 3];
        float4 g0 = *(const float4*)(Y + (size_t)d0 * 128 + c4);
        float4 g1 = *(const float4*)(Y + (size_t)d1 * 128 + c4);
        float4 g2 = *(const float4*)(Y + (size_t)d2 * 128 + c4);
        float4 g3 = *(const float4*)(Y + (size_t)d3 * 128 + c4);
        a0.x += g0.x; a0.y += g0.y; a0.z += g0.z; a0.w += g0.w;
        a1.x += g1.x; a1.y += g1.y; a1.z += g1.z; a1.w += g1.w;
        a2.x += g2.x; a2.y += g2.y; a2.z += g2.z; a2.w += g2.w;
        a3.x += g3.x; a3.y += g3.y; a3.z += g3.z; a3.w += g3.w;
    }
    for (; i < e; ++i) {
        int d = perm[i];
        float4 g = *(const float4*)(Y + (size_t)d * 128 + c4);
        a0.x += g.x; a0.y += g.y; a0.z += g.z; a0.w += g.w;
    }
    float4 hv;
    hv.x = (a0.x + a1.x) + (a2.x + a3.x);
    hv.y = (a0.y + a1.y) + (a2.y + a3.y);
    hv.z = (a0.z + a1.z) + (a2.z + a3.z);
    hv.w = (a0.w + a1.w) + (a2.w + a3.w);

    float4 c0 = *(const float4*)(Qt0 + c4);
    float4 c1 = *(const float4*)(Qt1 + c4);
    float4 c2 = *(const float4*)(Qt2 + c4);
    float p0 = hv.x * c0.x + hv.y * c0.y + hv.z * c0.z + hv.w * c0.w;
    float p1 = hv.x * c1.x + hv.y * c1.y + hv.z * c1.z + hv.w * c1.w;
    float p2 = hv.x * c2.x + hv.y * c2.y + hv.z * c2.z + hv.w * c2.w;
    #pragma unroll
    for (int off = 16; off > 0; off >>= 1) {
        p0 += __shfl_down(p0, off, 32);
        p1 += __shfl_down(p1, off, 32);
        p2 += __shfl_down(p2, off, 32);
    }
    if ((lane & 31) == 0) {
        float nv = nrm[node];
        float n2 = nv * nv;
        z4[node] = make_float4(n2 * p0, n2 * p1, n2 * p2, 0.f);
    }
}

// ---------------- second aggregation over 3-scalar z (16 B/edge gather) ----------------

__global__ __launch_bounds__(256) void k_aggp(const float4* __restrict__ z4, const int* __restrict__ row_start,
                                              const int* __restrict__ perm, const float* __restrict__ nrm,
                                              float* __restrict__ r0s, float* __restrict__ r1v,
                                              float* __restrict__ av, int n) {
    int i = blockIdx.x * 256 + threadIdx.x;
    if (i >= n) return;
    int s = row_start[i], e = row_start[i + 1];
    float p0 = 0.f, p1 = 0.f, p2 = 0.f;
    for (int j = s; j < e; ++j) {
        float4 v = z4[perm[j]];
        p0 += v.x; p1 += v.y; p2 += v.z;
    }
    float nv = nrm[i];
    r0s[i] = nv * p0;
    r1v[i] = nv * p1;
    av[i] = nv * p2;
}

// ---------------- edge outputs ----------------

__global__ __launch_bounds__(256) void k_edge_out(const int* __restrict__ esrc, const int* __restrict__ edst,
                                                  const int* __restrict__ sfake, const int* __restrict__ dfake,
                                                  const float* __restrict__ r0s, const float* __restrict__ r1v,
                                                  const float* __restrict__ av, float* __restrict__ out,
                                                  int E, int n) {
    int e = blockIdx.x * 256 + threadIdx.x;
    if (e >= E) return;
    int s = esrc[e], d = edst[e];
    int sf = sfake[e]; sf = sf < 0 ? 0 : (sf >= n ? n - 1 : sf);
    int df = dfake[e]; df = df < 0 ? 0 : (df >= n ? n - 1 : df);
    float as = av[s], ad = av[d], adf = av[df];
    out[e]             = expf(r0s[s] + r0s[d]);
    out[(size_t)E + e] = expf(r1v[s] + r1v[d]);
    out[(size_t)2 * E + e] = 1.f / (1.f + expf(-(as * ad)));
    out[(size_t)3 * E + e] = expf(r0s[sf] + 128.f * r1v[df]);
    out[(size_t)4 * E + e] = expf(r1v[sf] + r1v[df]);
    out[(size_t)5 * E + e] = 1.f / (1.f + expf(-(as * adf)));
}

// ---------------- launch ----------------

extern "C" void kernel_launch(void* const* d_in, const int* in_sizes, int n_in,
                              void* d_out, int out_size, void* d_ws, size_t ws_size,
                              hipStream_t stream) {
    const float* h       = (const float*)d_in[0];
    const float* w_gcn0  = (const float*)d_in[1];
    const float* w_gcn1  = (const float*)d_in[2];
    const float* w_rate0 = (const float*)d_in[3];
    const float* w_rate1 = (const float*)d_in[4];
    const float* w_alpha = (const float*)d_in[5];
    const int* edge_src  = (const int*)d_in[6];
    const int* edge_dst  = (const int*)d_in[7];
    const int* src_fake  = (const int*)d_in[8];
    const int* dst_fake  = (const int*)d_in[9];
    float* out = (float*)d_out;

    const int N = NN, E = EE;

    char* p = (char*)d_ws;
    auto alloc = [&](size_t bytes) {
        char* r = p;
        p += (bytes + 255) & ~(size_t)255;
        return r;
    };
    float* Y        = (float*)alloc((size_t)N * 128 * 4);
    int* perm       = (int*)alloc((size_t)E * 4);
    unsigned int* pk = (unsigned int*)alloc((size_t)E * 4);
    int* row_start  = (int*)alloc((size_t)(N + 1) * 4);
    float* nrm      = (float*)alloc((size_t)N * 4);
    float4* z4      = (float4*)alloc((size_t)N * 16);
    float* r0s      = (float*)alloc((size_t)N * 4);
    float* r1v      = (float*)alloc((size_t)N * 4);
    float* av       = (float*)alloc((size_t)N * 4);
    float* Qt0      = (float*)alloc(512);
    float* Qt1      = (float*)alloc(512);
    float* Qt2      = (float*)alloc(512);
    int* gbcnt      = (int*)alloc(KB * 4);
    int* bstart     = (int*)alloc((KB + 1) * 4);
    int* gcur       = (int*)alloc(KB * 4);

    hipMemsetAsync(gbcnt, 0, KB * 4, stream);

    int ebl4k = (E + 4095) / 4096;
    k_countB<<<ebl4k, 256, 0, stream>>>(edge_src, gbcnt, E);
    k_bscan<<<1, KB, 0, stream>>>(gbcnt, bstart, gcur, E);
    k_partA<<<ebl4k, 256, 0, stream>>>(edge_src, edge_dst, gcur, pk, E);
    k_partB<<<KB, 256, 0, stream>>>(pk, bstart, row_start, nrm, perm, N, E);
    k_qmat<<<1, 128, 0, stream>>>(w_gcn1, w_rate0, w_rate1, w_alpha, Qt0, Qt1, Qt2);

    dim3 mmg((N + 63) / 64, 2);
    int aggb = (((N + 1) / 2) * 64 + 255) / 256;

    k_mm<<<mmg, 256, 0, stream>>>(h, w_gcn0, nrm, Y, N);
    k_aggz<<<aggb, 256, 0, stream>>>(Y, row_start, perm, nrm, Qt0, Qt1, Qt2, z4, N);
    k_aggp<<<(N + 255) / 256, 256, 0, stream>>>(z4, row_start, perm, nrm, r0s, r1v, av, N);
    k_edge_out<<<(E + 255) / 256, 256, 0, stream>>>(edge_src, edge_dst, src_fake, dst_fake, r0s, r1v, av, out, E, N);
}